// Round 15
// baseline (1072.546 us; speedup 1.0000x reference)
//
#include <hip/hip_runtime.h>
#include <math.h>

#define B_  32
#define C_  256
#define H_  56
#define W_  56
#define CG_ 64
#define NG_ 4
#define P_  7
#define N_  49
#define XPP_ 52
#define PLP_ 57
#define PLANE_ (H_*W_)
#define NBC_ (B_*C_)
#define EPS_ 1e-5f

// DIAGNOSTIC ROUND: each kernel repeats its (idempotent) body REP times so all
// five exceed the harness fill dispatches (~58us) and surface in rocprof top-5
// with per-kernel counters. dur/REP = warm per-kernel cost.
#define REP1 6
#define REP2 32
#define REP3 16
#define REP4 24
#define REP5 5

typedef float f4v __attribute__((ext_vector_type(4)));
typedef short s4v __attribute__((ext_vector_type(4)));
typedef short s8v __attribute__((ext_vector_type(8)));
typedef unsigned int uint32;

__device__ __forceinline__ float sig_(float v) { return 1.0f / (1.0f + expf(-v)); }

__device__ __forceinline__ short f2bf_(float f) {
  uint32 u = __builtin_bit_cast(uint32, f);
  u = (u + 0x7FFFu + ((u >> 16) & 1u)) >> 16;
  return (short)u;
}
__device__ __forceinline__ float bf2f_(short s) {
  uint32 u = ((uint32)(unsigned short)s) << 16;
  return __builtin_bit_cast(float, u);
}

// ---------------- K1: row & col means + bf16 copy (padded LDS) ----------------
__global__ __launch_bounds__(256) void k1_means_bf(const float* __restrict__ x,
                                                   float* __restrict__ xh,
                                                   float* __restrict__ xw,
                                                   short* __restrict__ xbf) {
  __shared__ float pl[H_ * PLP_];
  const int bc = blockIdx.x, t = threadIdx.x;
  #pragma unroll 1
  for (int rep = 0; rep < REP1; ++rep) {
    const f4v* src = (const f4v*)(x + (size_t)bc * PLANE_);
    s4v* bdst = (s4v*)(xbf + (size_t)bc * PLANE_);
    for (int i = t; i < PLANE_ / 4; i += 256) {
      const f4v v = src[i];
      const int h = i / 14, c4 = i % 14;
      const int base = h * PLP_ + 4 * c4;
      pl[base]     = v.x; pl[base + 1] = v.y;
      pl[base + 2] = v.z; pl[base + 3] = v.w;
      s4v b;
      b.x = f2bf_(v.x); b.y = f2bf_(v.y); b.z = f2bf_(v.z); b.w = f2bf_(v.w);
      bdst[i] = b;
    }
    __syncthreads();
    if (t < H_) {
      float s = 0.f;
      #pragma unroll
      for (int w = 0; w < W_; ++w) s += pl[t * PLP_ + w];
      xh[(size_t)bc * H_ + t] = s * (1.0f / W_);
    } else if (t >= 64 && t < 64 + W_) {
      const int w = t - 64;
      float s = 0.f;
      #pragma unroll
      for (int h = 0; h < H_; ++h) s += pl[h * PLP_ + w];
      xw[(size_t)bc * W_ + w] = s * (1.0f / H_);
    }
    __syncthreads();
  }
}

// ------- K2: depthwise conv + GroupNorm(4) + sigmoid -------
__global__ __launch_bounds__(256) void k2_convgn(
    const float* __restrict__ inh, const float* __restrict__ inw,
    float* __restrict__ Ah, float* __restrict__ Aw,
    const float* __restrict__ h0, const float* __restrict__ h1,
    const float* __restrict__ h2, const float* __restrict__ h3,
    const float* __restrict__ w0, const float* __restrict__ w1,
    const float* __restrict__ w2, const float* __restrict__ w3,
    const float* __restrict__ gnh_w, const float* __restrict__ gnh_b,
    const float* __restrict__ gnw_w, const float* __restrict__ gnw_b) {
  __shared__ float sin_[CG_ * H_];
  __shared__ float sconv[CG_ * H_];
  __shared__ float redS[4], redQ[4];
  __shared__ float sMu, sRs;
  const int g = blockIdx.x, b = blockIdx.y, zz = blockIdx.z, t = threadIdx.x;
  const float* in = zz ? inw : inh;
  float* outb = zz ? Aw : Ah;
  const float* wt = zz ? ((g == 0) ? w0 : (g == 1) ? w1 : (g == 2) ? w2 : w3)
                       : ((g == 0) ? h0 : (g == 1) ? h1 : (g == 2) ? h2 : h3);
  const float* gw = zz ? gnw_w : gnh_w;
  const float* gb = zz ? gnw_b : gnh_b;
  const size_t base = ((size_t)b * C_ + (size_t)g * CG_) * H_;
  const int k = 3 + 2 * g, pad = k / 2;
  #pragma unroll 1
  for (int rep = 0; rep < REP2; ++rep) {
    for (int i = t; i < CG_ * H_; i += 256) sin_[i] = in[base + i];
    __syncthreads();
    float lsum = 0.f, lsq = 0.f;
    for (int i = t; i < CG_ * H_; i += 256) {
      const int cc = i / H_, l = i % H_;
      float s = 0.f;
      for (int j = 0; j < k; ++j) {
        const int ll = l + j - pad;
        if (ll >= 0 && ll < H_) s += sin_[cc * H_ + ll] * wt[cc * k + j];
      }
      sconv[i] = s;
      lsum += s; lsq += s * s;
    }
    #pragma unroll
    for (int m = 32; m >= 1; m >>= 1) { lsum += __shfl_xor(lsum, m); lsq += __shfl_xor(lsq, m); }
    if ((t & 63) == 0) { redS[t >> 6] = lsum; redQ[t >> 6] = lsq; }
    __syncthreads();
    if (t == 0) {
      const float S = redS[0] + redS[1] + redS[2] + redS[3];
      const float Q = redQ[0] + redQ[1] + redQ[2] + redQ[3];
      const float mu = S / (float)(CG_ * H_);
      sMu = mu; sRs = rsqrtf(Q / (float)(CG_ * H_) - mu * mu + EPS_);
    }
    __syncthreads();
    const float mu = sMu, rs = sRs;
    for (int i = t; i < CG_ * H_; i += 256) {
      const int c = g * CG_ + i / H_;
      outb[base + i] = sig_((sconv[i] - mu) * rs * gw[c] + gb[c]);
    }
    __syncthreads();
  }
}

// ---- K3: 4 planes/block, barrier-free, wave-shuffle pool (bf16 x) ----
__global__ __launch_bounds__(448) void k3_pool_bf4(const short* __restrict__ xbf,
    const float* __restrict__ Ah, const float* __restrict__ Aw,
    float* __restrict__ xp) {
  const int t = threadIdx.x;
  const int wv = t >> 6;
  const int ln = t & 63;
  const int r  = ln >> 3;
  const int pw = ln & 7;
  const int h  = 8 * wv + r;
  const bool act = (pw < 7);
  #pragma unroll 1
  for (int rep = 0; rep < REP3; ++rep) {
    #pragma unroll
    for (int c = 0; c < 4; ++c) {
      const int bc = blockIdx.x * 4 + c;
      float s = 0.f;
      if (act) {
        const s8v b = ((const s8v*)(xbf + (size_t)bc * PLANE_))[h * 7 + pw];
        const f4v* aw4 = (const f4v*)(Aw + (size_t)bc * W_);
        const f4v awa = aw4[2 * pw];
        const f4v awb = aw4[2 * pw + 1];
        const float ahh = Ah[(size_t)bc * H_ + h];
        s = (bf2f_(b[0]) * awa.x + bf2f_(b[1]) * awa.y
           + bf2f_(b[2]) * awa.z + bf2f_(b[3]) * awa.w
           + bf2f_(b[4]) * awb.x + bf2f_(b[5]) * awb.y
           + bf2f_(b[6]) * awb.z + bf2f_(b[7]) * awb.w) * ahh;
      }
      s += __shfl_xor(s, 8);
      s += __shfl_xor(s, 16);
      s += __shfl_xor(s, 32);
      if (act && r == 0)
        xp[(size_t)bc * XPP_ + wv * 7 + pw] = s * (1.0f / 64.0f);
      if (wv == 6 && ln >= 56 && ln < 59)
        xp[(size_t)bc * XPP_ + 49 + (ln - 56)] = 0.f;
    }
  }
}

// ------- K4: GN(1) + channel attention -> Mc -------
__global__ __launch_bounds__(256) void k4_attn(const float* __restrict__ xp,
    const float* __restrict__ gw, const float* __restrict__ gb,
    const float* __restrict__ wq, const float* __restrict__ wk, const float* __restrict__ wv,
    float* __restrict__ Mc) {
  __shared__ __align__(16) float xn[C_ * XPP_];
  __shared__ float vbar[C_];
  __shared__ float swk[C_];
  __shared__ float redS[4], redQ[4];
  __shared__ float sMu, sRs;
  const int chunk = blockIdx.x, b = blockIdx.y, t = threadIdx.x;
  const f4v* src4 = (const f4v*)(xp + (size_t)b * C_ * XPP_);
  f4v* xn4 = (f4v*)xn;
  #pragma unroll 1
  for (int rep = 0; rep < REP4; ++rep) {
    float lsum = 0.f, lsq = 0.f;
    #pragma unroll
    for (int j = 0; j < 13; ++j) {
      const int i = t + 256 * j;
      const f4v v = src4[i];
      xn4[i] = v;
      lsum += v.x + v.y + v.z + v.w;
      lsq  += v.x * v.x + v.y * v.y + v.z * v.z + v.w * v.w;
    }
    swk[t] = wk[t];
    #pragma unroll
    for (int m = 32; m >= 1; m >>= 1) { lsum += __shfl_xor(lsum, m); lsq += __shfl_xor(lsq, m); }
    if ((t & 63) == 0) { redS[t >> 6] = lsum; redQ[t >> 6] = lsq; }
    __syncthreads();
    if (t == 0) {
      const float S = redS[0] + redS[1] + redS[2] + redS[3];
      const float Q = redQ[0] + redQ[1] + redQ[2] + redQ[3];
      const float mu = S / (float)(C_ * N_);
      sMu = mu; sRs = rsqrtf(Q / (float)(C_ * N_) - mu * mu + EPS_);
    }
    __syncthreads();
    const float mu = sMu, rs = sRs;
    #pragma unroll
    for (int j = 0; j < 13; ++j) {
      const int i = t + 256 * j;
      const int c = i / 13, kk = i - c * 13;
      f4v v = xn4[i];
      v.x = (v.x - mu) * rs * gw[c] + gb[c];
      v.y = (v.y - mu) * rs * gw[c] + gb[c];
      v.z = (v.z - mu) * rs * gw[c] + gb[c];
      v.w = (v.w - mu) * rs * gw[c] + gb[c];
      if (kk == 12) { v.y = 0.f; v.z = 0.f; v.w = 0.f; }
      xn4[i] = v;
    }
    __syncthreads();
    {
      const f4v* row = (const f4v*)&xn[t * XPP_];
      f4v a = row[0];
      #pragma unroll
      for (int j = 1; j < 13; ++j) a += row[j];
      vbar[t] = wv[t] * (a.x + a.y + a.z + a.w) * (1.0f / N_);
    }
    __syncthreads();

    const int rg = t >> 4, q16 = t & 15;
    const int c0 = chunk * 32 + rg * 2;
    f4v qa[13], qb[13];
    {
      const f4v* r0 = (const f4v*)&xn[c0 * XPP_];
      const f4v* r1 = (const f4v*)&xn[(c0 + 1) * XPP_];
      #pragma unroll
      for (int j = 0; j < 13; ++j) { qa[j] = r0[j]; qb[j] = r1[j]; }
    }
    const float qs0 = wq[c0] * (1.0f / 7.0f);
    const float qs1 = wq[c0 + 1] * (1.0f / 7.0f);
    float s0[16], s1[16], vb[16];
    #pragma unroll
    for (int dd = 0; dd < 16; ++dd) {
      const int d = q16 + 16 * dd;
      const f4v* kb = (const f4v*)&xn[d * XPP_];
      f4v a0 = {0.f, 0.f, 0.f, 0.f}, a1 = {0.f, 0.f, 0.f, 0.f};
      #pragma unroll
      for (int j = 0; j < 13; ++j) {
        const f4v kv = kb[j];
        a0 += qa[j] * kv;
        a1 += qb[j] * kv;
      }
      const float wkd = swk[d];
      s0[dd] = (a0.x + a0.y + a0.z + a0.w) * qs0 * wkd;
      s1[dd] = (a1.x + a1.y + a1.z + a1.w) * qs1 * wkd;
      vb[dd] = vbar[d];
    }
    float m0 = -INFINITY, m1 = -INFINITY;
    #pragma unroll
    for (int dd = 0; dd < 16; ++dd) { m0 = fmaxf(m0, s0[dd]); m1 = fmaxf(m1, s1[dd]); }
    #pragma unroll
    for (int msk = 1; msk < 16; msk <<= 1) {
      m0 = fmaxf(m0, __shfl_xor(m0, msk, 16));
      m1 = fmaxf(m1, __shfl_xor(m1, msk, 16));
    }
    float e0 = 0.f, a0 = 0.f, e1 = 0.f, a1 = 0.f;
    #pragma unroll
    for (int dd = 0; dd < 16; ++dd) {
      const float x0 = expf(s0[dd] - m0);
      const float x1 = expf(s1[dd] - m1);
      e0 += x0; a0 += x0 * vb[dd];
      e1 += x1; a1 += x1 * vb[dd];
    }
    #pragma unroll
    for (int msk = 1; msk < 16; msk <<= 1) {
      e0 += __shfl_xor(e0, msk, 16); a0 += __shfl_xor(a0, msk, 16);
      e1 += __shfl_xor(e1, msk, 16); a1 += __shfl_xor(a1, msk, 16);
    }
    if (q16 == 0) {
      Mc[(size_t)b * C_ + c0]     = sig_(a0 / e0);
      Mc[(size_t)b * C_ + c0 + 1] = sig_(a1 / e1);
    }
    __syncthreads();
  }
}

// ---- K5: 4 planes/block, barrier-free (bf16 x) ----
__global__ __launch_bounds__(448) void k5_out_bf4(const short* __restrict__ xbf,
    const float* __restrict__ Ah, const float* __restrict__ Aw,
    const float* __restrict__ Mc, float* __restrict__ out) {
  const int t = threadIdx.x;
  if (t >= H_ * P_) return;
  const int h = t / P_, pw = t % P_;
  #pragma unroll 1
  for (int rep = 0; rep < REP5; ++rep) {
    #pragma unroll
    for (int c = 0; c < 4; ++c) {
      const int bc = blockIdx.x * 4 + c;
      const s8v b = ((const s8v*)(xbf + (size_t)bc * PLANE_))[t];
      const f4v* aw4 = (const f4v*)(Aw + (size_t)bc * W_);
      const f4v awa = aw4[2 * pw];
      const f4v awb = aw4[2 * pw + 1];
      const float a = Ah[(size_t)bc * H_ + h] * Mc[bc];
      f4v o1, o2;
      o1.x = bf2f_(b[0]) * a * awa.x; o1.y = bf2f_(b[1]) * a * awa.y;
      o1.z = bf2f_(b[2]) * a * awa.z; o1.w = bf2f_(b[3]) * a * awa.w;
      o2.x = bf2f_(b[4]) * a * awb.x; o2.y = bf2f_(b[5]) * a * awb.y;
      o2.z = bf2f_(b[6]) * a * awb.z; o2.w = bf2f_(b[7]) * a * awb.w;
      f4v* oo = (f4v*)(out + (size_t)bc * PLANE_);
      oo[2 * t]     = o1;
      oo[2 * t + 1] = o2;
    }
  }
}

extern "C" void kernel_launch(void* const* d_in, const int* in_sizes, int n_in,
                              void* d_out, int out_size, void* d_ws, size_t ws_size,
                              hipStream_t stream) {
  const float* x     = (const float*)d_in[0];
  const float* dwh0  = (const float*)d_in[1];
  const float* dww0  = (const float*)d_in[2];
  const float* dwh1  = (const float*)d_in[3];
  const float* dww1  = (const float*)d_in[4];
  const float* dwh2  = (const float*)d_in[5];
  const float* dww2  = (const float*)d_in[6];
  const float* dwh3  = (const float*)d_in[7];
  const float* dww3  = (const float*)d_in[8];
  const float* gnh_w = (const float*)d_in[9];
  const float* gnh_b = (const float*)d_in[10];
  const float* gnw_w = (const float*)d_in[11];
  const float* gnw_b = (const float*)d_in[12];
  const float* gn1_w = (const float*)d_in[13];
  const float* gn1_b = (const float*)d_in[14];
  const float* wq    = (const float*)d_in[15];
  const float* wk    = (const float*)d_in[16];
  const float* wv    = (const float*)d_in[17];
  float* out = (float*)d_out;

  float* ws   = (float*)d_ws;
  float* bufh = ws;
  float* bufw = bufh + (size_t)B_ * C_ * H_;
  float* Ah   = bufw + (size_t)B_ * C_ * W_;
  float* Aw   = Ah   + (size_t)B_ * C_ * H_;
  float* xp   = Aw   + (size_t)B_ * C_ * W_;
  float* Mc   = xp   + (size_t)B_ * C_ * XPP_;
  short* xbf  = (short*)(Mc + (size_t)B_ * C_);

  k1_means_bf<<<NBC_, 256, 0, stream>>>(x, bufh, bufw, xbf);
  k2_convgn<<<dim3(NG_, B_, 2), 256, 0, stream>>>(bufh, bufw, Ah, Aw,
      dwh0, dwh1, dwh2, dwh3, dww0, dww1, dww2, dww3,
      gnh_w, gnh_b, gnw_w, gnw_b);
  k3_pool_bf4<<<NBC_ / 4, 448, 0, stream>>>(xbf, Ah, Aw, xp);
  k4_attn<<<dim3(8, B_), 256, 0, stream>>>(xp, gn1_w, gn1_b, wq, wk, wv, Mc);
  k5_out_bf4<<<NBC_ / 4, 448, 0, stream>>>(xbf, Ah, Aw, Mc, out);
}

// Round 16
// 82.638 us; speedup vs baseline: 12.9789x; 12.9789x over previous
//
#include <hip/hip_runtime.h>
#include <math.h>

#define B_  32
#define C_  256
#define H_  56
#define W_  56
#define CG_ 64
#define NG_ 4
#define P_  7
#define N_  49
#define XPP_ 52
#define PLP_ 57
#define PLANE_ (H_*W_)
#define NBC_ (B_*C_)
#define EPS_ 1e-5f

typedef float f4v __attribute__((ext_vector_type(4)));
typedef short s4v __attribute__((ext_vector_type(4)));
typedef short s8v __attribute__((ext_vector_type(8)));
typedef unsigned int uint32;

__device__ __forceinline__ float sig_(float v) { return 1.0f / (1.0f + expf(-v)); }

__device__ __forceinline__ short f2bf_(float f) {
  uint32 u = __builtin_bit_cast(uint32, f);
  u = (u + 0x7FFFu + ((u >> 16) & 1u)) >> 16;
  return (short)u;
}
__device__ __forceinline__ float bf2f_(short s) {
  uint32 u = ((uint32)(unsigned short)s) << 16;
  return __builtin_bit_cast(float, u);
}

// ---------------- K1: row & col means + bf16 copy (padded LDS) ----------------
__global__ __launch_bounds__(256) void k1_means_bf(const float* __restrict__ x,
                                                   float* __restrict__ xh,
                                                   float* __restrict__ xw,
                                                   short* __restrict__ xbf) {
  __shared__ float pl[H_ * PLP_];
  const int bc = blockIdx.x, t = threadIdx.x;
  const f4v* src = (const f4v*)(x + (size_t)bc * PLANE_);
  s4v* bdst = (s4v*)(xbf + (size_t)bc * PLANE_);
  for (int i = t; i < PLANE_ / 4; i += 256) {
    const f4v v = src[i];
    const int h = i / 14, c4 = i % 14;
    const int base = h * PLP_ + 4 * c4;
    pl[base]     = v.x; pl[base + 1] = v.y;
    pl[base + 2] = v.z; pl[base + 3] = v.w;
    s4v b;
    b.x = f2bf_(v.x); b.y = f2bf_(v.y); b.z = f2bf_(v.z); b.w = f2bf_(v.w);
    bdst[i] = b;
  }
  __syncthreads();
  if (t < H_) {
    float s = 0.f;
    #pragma unroll
    for (int w = 0; w < W_; ++w) s += pl[t * PLP_ + w];
    xh[(size_t)bc * H_ + t] = s * (1.0f / W_);
  } else if (t >= 64 && t < 64 + W_) {
    const int w = t - 64;
    float s = 0.f;
    #pragma unroll
    for (int h = 0; h < H_; ++h) s += pl[h * PLP_ + w];
    xw[(size_t)bc * W_ + w] = s * (1.0f / H_);
  }
}

// ------- K2: conv + GroupNorm(4) + sigmoid. 896 thr (14 waves), reg-windowed conv -------
template<int K>
__device__ __forceinline__ void conv_body(const float* __restrict__ sin_,
                                          const float* __restrict__ swt,
                                          int cc, int l0,
                                          float res[4], float& lsum, float& lsq) {
  constexpr int PAD = K / 2;
  float w[K];
  #pragma unroll
  for (int j = 0; j < K; ++j) w[j] = swt[cc * K + j];
  float win[K + 3];
  #pragma unroll
  for (int jj = 0; jj < K + 3; ++jj) {
    const int idx = l0 - PAD + jj;
    win[jj] = (idx >= 0 && idx < H_) ? sin_[cc * H_ + idx] : 0.f;
  }
  #pragma unroll
  for (int p = 0; p < 4; ++p) {
    float s = 0.f;
    #pragma unroll
    for (int j = 0; j < K; ++j) s += win[p + j] * w[j];
    res[p] = s;
    lsum += s; lsq += s * s;
  }
}

__global__ __launch_bounds__(896) void k2_convgn(
    const float* __restrict__ inh, const float* __restrict__ inw,
    float* __restrict__ Ah, float* __restrict__ Aw,
    const float* __restrict__ h0, const float* __restrict__ h1,
    const float* __restrict__ h2, const float* __restrict__ h3,
    const float* __restrict__ w0, const float* __restrict__ w1,
    const float* __restrict__ w2, const float* __restrict__ w3,
    const float* __restrict__ gnh_w, const float* __restrict__ gnh_b,
    const float* __restrict__ gnw_w, const float* __restrict__ gnw_b) {
  __shared__ __align__(16) float sin_[CG_ * H_];   // 14 KB
  __shared__ float swt[CG_ * 9];                   // up to 2.25 KB
  __shared__ float redS[14], redQ[14];
  __shared__ float sMu, sRs;
  const int g = blockIdx.x, b = blockIdx.y, zz = blockIdx.z, t = threadIdx.x;
  const float* in = zz ? inw : inh;
  float* outb = zz ? Aw : Ah;
  const float* wt = zz ? ((g == 0) ? w0 : (g == 1) ? w1 : (g == 2) ? w2 : w3)
                       : ((g == 0) ? h0 : (g == 1) ? h1 : (g == 2) ? h2 : h3);
  const float* gw = zz ? gnw_w : gnh_w;
  const float* gb = zz ? gnw_b : gnh_b;
  const size_t base = ((size_t)b * C_ + (size_t)g * CG_) * H_;
  const int k = 3 + 2 * g;

  // stage slab (896 f4v, one per thread) + weights
  ((f4v*)sin_)[t] = ((const f4v*)(in + base))[t];
  if (t < CG_ * k) swt[t] = wt[t];
  __syncthreads();

  const int cc = t / 14, quad = t % 14;    // f4v index == t
  const int l0 = 4 * quad;
  float res[4];
  float lsum = 0.f, lsq = 0.f;
  if (k == 3)      conv_body<3>(sin_, swt, cc, l0, res, lsum, lsq);
  else if (k == 5) conv_body<5>(sin_, swt, cc, l0, res, lsum, lsq);
  else if (k == 7) conv_body<7>(sin_, swt, cc, l0, res, lsum, lsq);
  else             conv_body<9>(sin_, swt, cc, l0, res, lsum, lsq);

  #pragma unroll
  for (int m = 32; m >= 1; m >>= 1) { lsum += __shfl_xor(lsum, m); lsq += __shfl_xor(lsq, m); }
  if ((t & 63) == 0) { redS[t >> 6] = lsum; redQ[t >> 6] = lsq; }
  __syncthreads();
  if (t == 0) {
    float S = 0.f, Q = 0.f;
    #pragma unroll
    for (int j = 0; j < 14; ++j) { S += redS[j]; Q += redQ[j]; }
    const float mu = S / (float)(CG_ * H_);
    sMu = mu; sRs = rsqrtf(Q / (float)(CG_ * H_) - mu * mu + EPS_);
  }
  __syncthreads();
  const float mu = sMu, rs = sRs;
  const int c = g * CG_ + cc;
  const float gwc = gw[c], gbc = gb[c];
  f4v o;
  o.x = sig_((res[0] - mu) * rs * gwc + gbc);
  o.y = sig_((res[1] - mu) * rs * gwc + gbc);
  o.z = sig_((res[2] - mu) * rs * gwc + gbc);
  o.w = sig_((res[3] - mu) * rs * gwc + gbc);
  ((f4v*)(outb + base))[t] = o;
}

// ---- K3: 4 planes/block, barrier-free, wave-shuffle pool (bf16 x) ----
__global__ __launch_bounds__(448) void k3_pool_bf4(const short* __restrict__ xbf,
    const float* __restrict__ Ah, const float* __restrict__ Aw,
    float* __restrict__ xp) {
  const int t = threadIdx.x;
  const int wv = t >> 6;
  const int ln = t & 63;
  const int r  = ln >> 3;
  const int pw = ln & 7;
  const int h  = 8 * wv + r;
  const bool act = (pw < 7);
  #pragma unroll
  for (int c = 0; c < 4; ++c) {
    const int bc = blockIdx.x * 4 + c;
    float s = 0.f;
    if (act) {
      const s8v b = ((const s8v*)(xbf + (size_t)bc * PLANE_))[h * 7 + pw];
      const f4v* aw4 = (const f4v*)(Aw + (size_t)bc * W_);
      const f4v awa = aw4[2 * pw];
      const f4v awb = aw4[2 * pw + 1];
      const float ahh = Ah[(size_t)bc * H_ + h];
      s = (bf2f_(b[0]) * awa.x + bf2f_(b[1]) * awa.y
         + bf2f_(b[2]) * awa.z + bf2f_(b[3]) * awa.w
         + bf2f_(b[4]) * awb.x + bf2f_(b[5]) * awb.y
         + bf2f_(b[6]) * awb.z + bf2f_(b[7]) * awb.w) * ahh;
    }
    s += __shfl_xor(s, 8);
    s += __shfl_xor(s, 16);
    s += __shfl_xor(s, 32);
    if (act && r == 0)
      xp[(size_t)bc * XPP_ + wv * 7 + pw] = s * (1.0f / 64.0f);
    if (wv == 6 && ln >= 56 && ln < 59)
      xp[(size_t)bc * XPP_ + 49 + (ln - 56)] = 0.f;
  }
}

// ------- K4: GN(1) + channel attention -> Mc. grid (8, B_), block 256. -------
__global__ __launch_bounds__(256) void k4_attn(const float* __restrict__ xp,
    const float* __restrict__ gw, const float* __restrict__ gb,
    const float* __restrict__ wq, const float* __restrict__ wk, const float* __restrict__ wv,
    float* __restrict__ Mc) {
  __shared__ __align__(16) float xn[C_ * XPP_];
  __shared__ float vbar[C_];
  __shared__ float swk[C_];
  __shared__ float redS[4], redQ[4];
  __shared__ float sMu, sRs;
  const int chunk = blockIdx.x, b = blockIdx.y, t = threadIdx.x;
  const f4v* src4 = (const f4v*)(xp + (size_t)b * C_ * XPP_);
  f4v* xn4 = (f4v*)xn;

  float lsum = 0.f, lsq = 0.f;
  #pragma unroll
  for (int j = 0; j < 13; ++j) {
    const int i = t + 256 * j;
    const f4v v = src4[i];
    xn4[i] = v;
    lsum += v.x + v.y + v.z + v.w;
    lsq  += v.x * v.x + v.y * v.y + v.z * v.z + v.w * v.w;
  }
  swk[t] = wk[t];
  #pragma unroll
  for (int m = 32; m >= 1; m >>= 1) { lsum += __shfl_xor(lsum, m); lsq += __shfl_xor(lsq, m); }
  if ((t & 63) == 0) { redS[t >> 6] = lsum; redQ[t >> 6] = lsq; }
  __syncthreads();
  if (t == 0) {
    const float S = redS[0] + redS[1] + redS[2] + redS[3];
    const float Q = redQ[0] + redQ[1] + redQ[2] + redQ[3];
    const float mu = S / (float)(C_ * N_);
    sMu = mu; sRs = rsqrtf(Q / (float)(C_ * N_) - mu * mu + EPS_);
  }
  __syncthreads();
  const float mu = sMu, rs = sRs;
  #pragma unroll
  for (int j = 0; j < 13; ++j) {
    const int i = t + 256 * j;
    const int c = i / 13, kk = i - c * 13;
    f4v v = xn4[i];
    v.x = (v.x - mu) * rs * gw[c] + gb[c];
    v.y = (v.y - mu) * rs * gw[c] + gb[c];
    v.z = (v.z - mu) * rs * gw[c] + gb[c];
    v.w = (v.w - mu) * rs * gw[c] + gb[c];
    if (kk == 12) { v.y = 0.f; v.z = 0.f; v.w = 0.f; }
    xn4[i] = v;
  }
  __syncthreads();
  {
    const f4v* row = (const f4v*)&xn[t * XPP_];
    f4v a = row[0];
    #pragma unroll
    for (int j = 1; j < 13; ++j) a += row[j];
    vbar[t] = wv[t] * (a.x + a.y + a.z + a.w) * (1.0f / N_);
  }
  __syncthreads();

  const int rg = t >> 4, q16 = t & 15;
  const int c0 = chunk * 32 + rg * 2;
  f4v qa[13], qb[13];
  {
    const f4v* r0 = (const f4v*)&xn[c0 * XPP_];
    const f4v* r1 = (const f4v*)&xn[(c0 + 1) * XPP_];
    #pragma unroll
    for (int j = 0; j < 13; ++j) { qa[j] = r0[j]; qb[j] = r1[j]; }
  }
  const float qs0 = wq[c0] * (1.0f / 7.0f);
  const float qs1 = wq[c0 + 1] * (1.0f / 7.0f);

  float s0[16], s1[16], vb[16];
  #pragma unroll
  for (int dd = 0; dd < 16; ++dd) {
    const int d = q16 + 16 * dd;
    const f4v* kb = (const f4v*)&xn[d * XPP_];
    f4v a0 = {0.f, 0.f, 0.f, 0.f}, a1 = {0.f, 0.f, 0.f, 0.f};
    #pragma unroll
    for (int j = 0; j < 13; ++j) {
      const f4v kv = kb[j];
      a0 += qa[j] * kv;
      a1 += qb[j] * kv;
    }
    const float wkd = swk[d];
    s0[dd] = (a0.x + a0.y + a0.z + a0.w) * qs0 * wkd;
    s1[dd] = (a1.x + a1.y + a1.z + a1.w) * qs1 * wkd;
    vb[dd] = vbar[d];
  }
  float m0 = -INFINITY, m1 = -INFINITY;
  #pragma unroll
  for (int dd = 0; dd < 16; ++dd) { m0 = fmaxf(m0, s0[dd]); m1 = fmaxf(m1, s1[dd]); }
  #pragma unroll
  for (int msk = 1; msk < 16; msk <<= 1) {
    m0 = fmaxf(m0, __shfl_xor(m0, msk, 16));
    m1 = fmaxf(m1, __shfl_xor(m1, msk, 16));
  }
  float e0 = 0.f, a0 = 0.f, e1 = 0.f, a1 = 0.f;
  #pragma unroll
  for (int dd = 0; dd < 16; ++dd) {
    const float x0 = expf(s0[dd] - m0);
    const float x1 = expf(s1[dd] - m1);
    e0 += x0; a0 += x0 * vb[dd];
    e1 += x1; a1 += x1 * vb[dd];
  }
  #pragma unroll
  for (int msk = 1; msk < 16; msk <<= 1) {
    e0 += __shfl_xor(e0, msk, 16); a0 += __shfl_xor(a0, msk, 16);
    e1 += __shfl_xor(e1, msk, 16); a1 += __shfl_xor(a1, msk, 16);
  }
  if (q16 == 0) {
    Mc[(size_t)b * C_ + c0]     = sig_(a0 / e0);
    Mc[(size_t)b * C_ + c0 + 1] = sig_(a1 / e1);
  }
}

// ---- K5: 4 planes/block, barrier-free (bf16 x) ----
__global__ __launch_bounds__(448) void k5_out_bf4(const short* __restrict__ xbf,
    const float* __restrict__ Ah, const float* __restrict__ Aw,
    const float* __restrict__ Mc, float* __restrict__ out) {
  const int t = threadIdx.x;
  if (t >= H_ * P_) return;
  const int h = t / P_, pw = t % P_;
  #pragma unroll
  for (int c = 0; c < 4; ++c) {
    const int bc = blockIdx.x * 4 + c;
    const s8v b = ((const s8v*)(xbf + (size_t)bc * PLANE_))[t];
    const f4v* aw4 = (const f4v*)(Aw + (size_t)bc * W_);
    const f4v awa = aw4[2 * pw];
    const f4v awb = aw4[2 * pw + 1];
    const float a = Ah[(size_t)bc * H_ + h] * Mc[bc];
    f4v o1, o2;
    o1.x = bf2f_(b[0]) * a * awa.x; o1.y = bf2f_(b[1]) * a * awa.y;
    o1.z = bf2f_(b[2]) * a * awa.z; o1.w = bf2f_(b[3]) * a * awa.w;
    o2.x = bf2f_(b[4]) * a * awb.x; o2.y = bf2f_(b[5]) * a * awb.y;
    o2.z = bf2f_(b[6]) * a * awb.z; o2.w = bf2f_(b[7]) * a * awb.w;
    f4v* oo = (f4v*)(out + (size_t)bc * PLANE_);
    oo[2 * t]     = o1;
    oo[2 * t + 1] = o2;
  }
}

extern "C" void kernel_launch(void* const* d_in, const int* in_sizes, int n_in,
                              void* d_out, int out_size, void* d_ws, size_t ws_size,
                              hipStream_t stream) {
  const float* x     = (const float*)d_in[0];
  const float* dwh0  = (const float*)d_in[1];
  const float* dww0  = (const float*)d_in[2];
  const float* dwh1  = (const float*)d_in[3];
  const float* dww1  = (const float*)d_in[4];
  const float* dwh2  = (const float*)d_in[5];
  const float* dww2  = (const float*)d_in[6];
  const float* dwh3  = (const float*)d_in[7];
  const float* dww3  = (const float*)d_in[8];
  const float* gnh_w = (const float*)d_in[9];
  const float* gnh_b = (const float*)d_in[10];
  const float* gnw_w = (const float*)d_in[11];
  const float* gnw_b = (const float*)d_in[12];
  const float* gn1_w = (const float*)d_in[13];
  const float* gn1_b = (const float*)d_in[14];
  const float* wq    = (const float*)d_in[15];
  const float* wk    = (const float*)d_in[16];
  const float* wv    = (const float*)d_in[17];
  float* out = (float*)d_out;

  float* ws   = (float*)d_ws;
  float* bufh = ws;
  float* bufw = bufh + (size_t)B_ * C_ * H_;
  float* Ah   = bufw + (size_t)B_ * C_ * W_;
  float* Aw   = Ah   + (size_t)B_ * C_ * H_;
  float* xp   = Aw   + (size_t)B_ * C_ * W_;
  float* Mc   = xp   + (size_t)B_ * C_ * XPP_;
  short* xbf  = (short*)(Mc + (size_t)B_ * C_);

  k1_means_bf<<<NBC_, 256, 0, stream>>>(x, bufh, bufw, xbf);
  k2_convgn<<<dim3(NG_, B_, 2), 896, 0, stream>>>(bufh, bufw, Ah, Aw,
      dwh0, dwh1, dwh2, dwh3, dww0, dww1, dww2, dww3,
      gnh_w, gnh_b, gnw_w, gnw_b);
  k3_pool_bf4<<<NBC_ / 4, 448, 0, stream>>>(xbf, Ah, Aw, xp);
  k4_attn<<<dim3(8, B_), 256, 0, stream>>>(xp, gn1_w, gn1_b, wq, wk, wv, Mc);
  k5_out_bf4<<<NBC_ / 4, 448, 0, stream>>>(xbf, Ah, Aw, Mc, out);
}